// Round 8
// baseline (860.957 us; speedup 1.0000x reference)
//
#include <hip/hip_runtime.h>
#include <hip/hip_bf16.h>

#define N_NODES 200000
#define N_EDGES 600000
#define N_GRAPHS 4000
#define EMB 128
#define LAYERS 5
#define BN_EPS 1e-5f

#define SCAN_CHUNK 2048                   // 256 threads x 8
#define N_CHUNKS ((N_NODES + SCAN_CHUNK - 1) / SCAN_CHUNK)   // 98

typedef __attribute__((ext_vector_type(8))) short short8;   // 8 bf16 (4 VGPRs)
typedef __attribute__((ext_vector_type(4))) float float4v;  // MFMA C/D

// split f32 -> bf16 hi (truncate) + bf16 lo (truncate of residual)
__device__ __forceinline__ void bf16split(float f, unsigned short& hi, unsigned short& lo) {
    unsigned u = __float_as_uint(f);
    hi = (unsigned short)(u >> 16);
    float hf = __uint_as_float((unsigned)hi << 16);
    lo = (unsigned short)(__float_as_uint(f - hf) >> 16);
}

// ---------------------------------------------------------------------------
// Fused prep kernel: 5 independent jobs partitioned by blockIdx.
//  [0, CNT)        edge histogram (src/dst degree)
//  [CNT, CB)       W split into swizzled bf16 hi/lo B-fragments
//  [CB, BN)        bond-combo table
//  [BN, GB)        BN scale/shift precompute
//  [GB, end)       graph boundaries from sorted batch
// ---------------------------------------------------------------------------
#define CNT_BLOCKS 2344
#define WP_BASE   CNT_BLOCKS
#define WP_BLOCKS 320
#define CB_BASE   (WP_BASE + WP_BLOCKS)
#define CB_BLOCKS 1280
#define BN_BASE   (CB_BASE + CB_BLOCKS)
#define BN_BLOCKS 3
#define GB_BASE   (BN_BASE + BN_BLOCKS)
#define GB_BLOCKS 16
#define PREP_BLOCKS (GB_BASE + GB_BLOCKS)

__global__ __launch_bounds__(256) void prep_all(
    const int* __restrict__ ei_src, const int* __restrict__ ei_dst,
    int* __restrict__ dsrc, int* __restrict__ ddst,
    const float* __restrict__ W, unsigned short* __restrict__ whi,
    unsigned short* __restrict__ wlo,
    const float* __restrict__ bemb, float* __restrict__ combo,
    const float* __restrict__ mean, const float* __restrict__ var,
    const float* __restrict__ gamma, const float* __restrict__ beta,
    float* __restrict__ S, float* __restrict__ T,
    const int* __restrict__ batch, int* __restrict__ gptr) {
    const int b = blockIdx.x, tid = threadIdx.x;
    if (b < CNT_BLOCKS) {
        const int e = b * 256 + tid;
        if (e < N_EDGES) {
            atomicAdd(&dsrc[ei_src[e]], 1);
            atomicAdd(&ddst[ei_dst[e]], 1);
        }
    } else if (b < CB_BASE) {
        const int idx = (b - WP_BASE) * 256 + tid;      // < 81920, exact
        const int l = idx >> 14, rem = idx & 16383;
        const int k = rem >> 7, n = rem & 127;
        unsigned short hi, lo;
        bf16split(W[idx], hi, lo);
        const int off = (l << 14) + ((((k >> 5) * 8 + (n >> 4)) * 64
                        + ((k >> 3) & 3) * 16 + (n & 15)) << 3) + (k & 7);
        whi[off] = hi;
        wlo[off] = lo;
    } else if (b < BN_BASE) {
        const int idx = (b - CB_BASE) * 256 + tid;      // < 327680, exact
        const int l = idx >> 16;
        const int c = (idx >> 7) & 511;
        const int ch = idx & 127;
        const int a0 = c & 7, a1 = (c >> 3) & 7, a2 = c >> 6;
        combo[(size_t)(l * 512 + c) * EMB + ch] =
            bemb[(size_t)((l * 3 + 0) * 8 + a0) * EMB + ch] +
            bemb[(size_t)((l * 3 + 1) * 8 + a1) * EMB + ch] +
            bemb[(size_t)((l * 3 + 2) * 8 + a2) * EMB + ch];
    } else if (b < GB_BASE) {
        const int i = (b - BN_BASE) * 256 + tid;
        if (i < LAYERS * EMB) {
            float s = gamma[i] / sqrtf(var[i] + BN_EPS);
            S[i] = s;
            T[i] = beta[i] - mean[i] * s;
        }
    } else {
        const int g = (b - GB_BASE) * 256 + tid;
        if (g > N_GRAPHS) return;
        if (g == N_GRAPHS) { gptr[g] = N_NODES; return; }
        int lo = 0, hi = N_NODES;
        while (lo < hi) {
            int mid = (lo + hi) >> 1;
            if (batch[mid] < g) lo = mid + 1; else hi = mid;
        }
        gptr[g] = lo;
    }
}

// ---------------------------------------------------------------------------
// scan1: per-chunk sums of ddst
// ---------------------------------------------------------------------------
__global__ __launch_bounds__(256) void scan1(const int* __restrict__ deg, int* __restrict__ partial) {
    __shared__ int sd[256];
    const int base = blockIdx.x * SCAN_CHUNK + threadIdx.x * 8;
    int s = 0;
#pragma unroll
    for (int i = 0; i < 8; ++i) { int idx = base + i; s += (idx < N_NODES) ? deg[idx] : 0; }
    sd[threadIdx.x] = s; __syncthreads();
    for (int off = 128; off > 0; off >>= 1) {
        if (threadIdx.x < off) sd[threadIdx.x] += sd[threadIdx.x + off];
        __syncthreads();
    }
    if (threadIdx.x == 0) partial[blockIdx.x] = sd[0];
}

// ---------------------------------------------------------------------------
// scan3: block computes its own offset from partials (scan2 eliminated),
// then exclusive-scans its chunk into rowptr.
// ---------------------------------------------------------------------------
__global__ __launch_bounds__(256) void scan3(const int* __restrict__ deg,
                                             const int* __restrict__ partial,
                                             int* __restrict__ rowptr) {
    __shared__ int sd[256];
    __shared__ int base_off;
    const int tid = threadIdx.x;
    if (tid == 0) {
        int acc = 0;
        for (int i = 0; i < (int)blockIdx.x; ++i) acc += partial[i];
        base_off = acc;
    }
    const int base = blockIdx.x * SCAN_CHUNK + tid * 8;
    int loc[8]; int s = 0;
#pragma unroll
    for (int i = 0; i < 8; ++i) { int idx = base + i; loc[i] = (idx < N_NODES) ? deg[idx] : 0; s += loc[i]; }
    sd[tid] = s; __syncthreads();
    for (int off = 1; off < 256; off <<= 1) {
        int v = (tid >= off) ? sd[tid - off] : 0;
        __syncthreads();
        sd[tid] += v;
        __syncthreads();
    }
    int excl = base_off + sd[tid] - s;
#pragma unroll
    for (int i = 0; i < 8; ++i) {
        int idx = base + i;
        if (idx < N_NODES) { rowptr[idx] = excl; excl += loc[i]; }
    }
    if (blockIdx.x == 0 && tid == 0) rowptr[N_NODES] = N_EDGES;
}

// ---------------------------------------------------------------------------
// Scatter edges into dst-CSR. Record: epk = src | combo<<18 ; enrm = norm.
// ---------------------------------------------------------------------------
__global__ void scatter_k(const int* __restrict__ srcs, const int* __restrict__ dsts,
                          const int* __restrict__ eattr, const int* __restrict__ dsrc,
                          const int* __restrict__ rowptr, int* __restrict__ fill,
                          int* __restrict__ epk, float* __restrict__ enrm) {
    int e = blockIdx.x * blockDim.x + threadIdx.x;
    if (e >= N_EDGES) return;
    const int s = srcs[e];
    const int d = dsts[e];
    const int pos = rowptr[d] + atomicAdd(&fill[d], 1);
    const int c = eattr[e * 3] | (eattr[e * 3 + 1] << 3) | (eattr[e * 3 + 2] << 6);
    epk[pos] = s | (c << 18);
    enrm[pos] = rsqrtf((float)(dsrc[s] + 1) * (float)(dsrc[d] + 1));
}

// ---------------------------------------------------------------------------
// MFMA phase for 1024-thread blocks: 32 rows x 128 cols, 16 waves, each wave
// one 16x16 C-tile over K=128 (4 ksteps x 3 split-terms). XLout stored
// NON-TEMPORAL (write stream must not evict the gather read set from L3).
// ---------------------------------------------------------------------------
__device__ __forceinline__ void mfma_tile32(
    const unsigned short (*Ah)[136], const unsigned short (*Al)[136],
    const short8* __restrict__ Bh, const short8* __restrict__ Bl,
    const float* __restrict__ bias, float* __restrict__ XLout,
    size_t rows, int tid) {
    const int wave = tid >> 6;          // 0..15
    const int lane = tid & 63;
    const int quad = lane >> 4;
    const int n15  = lane & 15;
    const int rt   = wave & 1;          // row-tile
    const int ct   = wave >> 1;         // col-tile 0..7
    const int arow = rt * 16 + n15;

    float4v acc = (float4v)(0.f);
#pragma unroll
    for (int ks = 0; ks < 4; ++ks) {
        const int k0 = ks * 32 + quad * 8;
        const short8 ah = *(const short8*)&Ah[arow][k0];
        const short8 al = *(const short8*)&Al[arow][k0];
        const short8 bh = Bh[(ks * 8 + ct) * 64 + lane];
        const short8 bl = Bl[(ks * 8 + ct) * 64 + lane];
        acc = __builtin_amdgcn_mfma_f32_16x16x32_bf16(ah, bh, acc, 0, 0, 0);
        acc = __builtin_amdgcn_mfma_f32_16x16x32_bf16(ah, bl, acc, 0, 0, 0);
        acc = __builtin_amdgcn_mfma_f32_16x16x32_bf16(al, bh, acc, 0, 0, 0);
    }

    const size_t rowBase = rows + rt * 16 + quad * 4;
    const int col = ct * 16 + n15;
    const float bc = bias[col];
#pragma unroll
    for (int r = 0; r < 4; ++r)
        __builtin_nontemporal_store(acc[r] + bc, &XLout[(rowBase + r) * EMB + col]);
}

// ---------------------------------------------------------------------------
// Fused atom-encoder + GEMM layer 0 (1024 threads): 32 half-waves x 1 row.
// ---------------------------------------------------------------------------
__global__ __launch_bounds__(1024, 8) void enc_gemm(
    const int* __restrict__ x, const float* __restrict__ aemb,
    const unsigned short* __restrict__ whi, const unsigned short* __restrict__ wlo,
    const float* __restrict__ bias, float* __restrict__ XL) {
    __shared__ unsigned short Ah[32][136];
    __shared__ unsigned short Al[32][136];
    const int tid = threadIdx.x;
    const int g = tid & 31, hw = tid >> 5;     // 32 half-waves
    const int c0 = g * 4;
    const size_t rows = (size_t)blockIdx.x * 32;

    {
        const size_t n = rows + hw;
        float4 acc = make_float4(0.f, 0.f, 0.f, 0.f);
#pragma unroll
        for (int ff = 0; ff < 9; ++ff) {
            const int v = x[n * 9 + ff];
            const float4 e = *(const float4*)&aemb[(size_t)(ff * 64 + v) * EMB + c0];
            acc.x += e.x; acc.y += e.y; acc.z += e.z; acc.w += e.w;
        }
        ushort4 hi, lo;
        bf16split(acc.x, hi.x, lo.x);
        bf16split(acc.y, hi.y, lo.y);
        bf16split(acc.z, hi.z, lo.z);
        bf16split(acc.w, hi.w, lo.w);
        *(ushort4*)&Ah[hw][c0] = hi;
        *(ushort4*)&Al[hw][c0] = lo;
    }
    __syncthreads();
    mfma_tile32(Ah, Al, (const short8*)whi, (const short8*)wlo, bias, XL, rows, tid);
}

// ---------------------------------------------------------------------------
// Fused gather(layer l) + BN_l + ReLU + GEMM(layer l+1) (1024 threads):
// 32 half-waves x 1 node gather (depth-2 pipelined: epk 2 ahead, rows 1
// ahead) -> LDS bf16 split -> 16-wave MFMA. h never touches HBM.
// ---------------------------------------------------------------------------
__global__ __launch_bounds__(1024, 8) void gather_gemm(
    const int* __restrict__ rowptr, const int* __restrict__ epk,
    const float* __restrict__ enrm, const float* __restrict__ combo,
    const float* __restrict__ root, const int* __restrict__ dsrc,
    const float* __restrict__ bnS, const float* __restrict__ bnT,
    const unsigned short* __restrict__ whi, const unsigned short* __restrict__ wlo,
    const float* __restrict__ bias,
    const float* __restrict__ XLin, float* __restrict__ XLout) {
    __shared__ unsigned short Ah[32][136];
    __shared__ unsigned short Al[32][136];
    const int tid = threadIdx.x;
    const int g = tid & 31, hw = tid >> 5;
    const int c0 = g * 4;
    const size_t rows = (size_t)blockIdx.x * 32;

    {
        const size_t n = rows + hw;
        const float4 r4 = *(const float4*)&root[c0];
        const float4 s4 = *(const float4*)&bnS[c0];
        const float4 t4 = *(const float4*)&bnT[c0];
        const float dinv = 1.0f / (float)(dsrc[n] + 1);
        const float4 xn = *(const float4*)&XLin[n * EMB + c0];
        float4 acc;
        acc.x = fmaxf(xn.x + r4.x, 0.f) * dinv;
        acc.y = fmaxf(xn.y + r4.y, 0.f) * dinv;
        acc.z = fmaxf(xn.z + r4.z, 0.f) * dinv;
        acc.w = fmaxf(xn.w + r4.w, 0.f) * dinv;

        const int beg = rowptr[n], end = rowptr[n + 1];
        int pkA = 0, pkB = 0; float wA = 0.f, wB = 0.f;
        if (beg < end)     { pkA = epk[beg];     wA = enrm[beg]; }
        if (beg + 1 < end) { pkB = epk[beg + 1]; wB = enrm[beg + 1]; }
        float4 xvA = make_float4(0.f, 0.f, 0.f, 0.f), cbA = xvA;
        if (beg < end) {
            xvA = *(const float4*)&XLin[(size_t)(pkA & 0x3FFFF) * EMB + c0];
            cbA = *(const float4*)&combo[(size_t)(pkA >> 18) * EMB + c0];
        }
        for (int e = beg; e < end; ++e) {
            const float4 xvC = xvA, cbC = cbA;
            const float wC = wA;
            pkA = pkB; wA = wB;
            if (e + 1 < end) {
                xvA = *(const float4*)&XLin[(size_t)(pkA & 0x3FFFF) * EMB + c0];
                cbA = *(const float4*)&combo[(size_t)(pkA >> 18) * EMB + c0];
            }
            if (e + 2 < end) { pkB = epk[e + 2]; wB = enrm[e + 2]; }
            acc.x += fmaxf(xvC.x + cbC.x, 0.f) * wC;
            acc.y += fmaxf(xvC.y + cbC.y, 0.f) * wC;
            acc.z += fmaxf(xvC.z + cbC.z, 0.f) * wC;
            acc.w += fmaxf(xvC.w + cbC.w, 0.f) * wC;
        }
        float4 h;
        h.x = fmaxf(fmaf(acc.x, s4.x, t4.x), 0.f);
        h.y = fmaxf(fmaf(acc.y, s4.y, t4.y), 0.f);
        h.z = fmaxf(fmaf(acc.z, s4.z, t4.z), 0.f);
        h.w = fmaxf(fmaf(acc.w, s4.w, t4.w), 0.f);
        ushort4 hi, lo;
        bf16split(h.x, hi.x, lo.x);
        bf16split(h.y, hi.y, lo.y);
        bf16split(h.z, hi.z, lo.z);
        bf16split(h.w, hi.w, lo.w);
        *(ushort4*)&Ah[hw][c0] = hi;
        *(ushort4*)&Al[hw][c0] = lo;
    }
    __syncthreads();
    mfma_tile32(Ah, Al, (const short8*)whi, (const short8*)wlo, bias, XLout, rows, tid);
}

// ---------------------------------------------------------------------------
// Fused final gather(layer 4) + BN4 + pool + head. One 512-thread block per
// graph: 16 half-waves stride the graph's nodes with register partials;
// LDS reduce; in-block head matvec. No global atomics.
// ---------------------------------------------------------------------------
__global__ __launch_bounds__(512) void gather_pool_head(
    const int* __restrict__ rowptr, const int* __restrict__ epk,
    const float* __restrict__ enrm, const float* __restrict__ combo,
    const float* __restrict__ root, const int* __restrict__ dsrc,
    const float* __restrict__ S4, const float* __restrict__ T4,
    const int* __restrict__ gptr, const float* __restrict__ XLin,
    const float* __restrict__ HW, const float* __restrict__ hb,
    float* __restrict__ OUT) {
    __shared__ float red[16][EMB];
    __shared__ float hr[EMB];
    const int gph = blockIdx.x;
    const int g = threadIdx.x & 31, hw = threadIdx.x >> 5;   // 16 half-waves
    const int c0 = g * 4;
    const int nbeg = gptr[gph], nend = gptr[gph + 1];

    const float4 r4 = *(const float4*)&root[c0];
    const float4 s4 = *(const float4*)&S4[c0];
    const float4 t4 = *(const float4*)&T4[c0];

    float4 seg = make_float4(0.f, 0.f, 0.f, 0.f);
    for (int n = nbeg + hw; n < nend; n += 16) {
        const float dinv = 1.0f / (float)(dsrc[n] + 1);
        const float4 xn = *(const float4*)&XLin[(size_t)n * EMB + c0];
        float4 acc;
        acc.x = fmaxf(xn.x + r4.x, 0.f) * dinv;
        acc.y = fmaxf(xn.y + r4.y, 0.f) * dinv;
        acc.z = fmaxf(xn.z + r4.z, 0.f) * dinv;
        acc.w = fmaxf(xn.w + r4.w, 0.f) * dinv;

        const int beg = rowptr[n], end = rowptr[n + 1];
        int pkA = 0, pkB = 0; float wA = 0.f, wB = 0.f;
        if (beg < end)     { pkA = epk[beg];     wA = enrm[beg]; }
        if (beg + 1 < end) { pkB = epk[beg + 1]; wB = enrm[beg + 1]; }
        float4 xvA = make_float4(0.f, 0.f, 0.f, 0.f), cbA = xvA;
        if (beg < end) {
            xvA = *(const float4*)&XLin[(size_t)(pkA & 0x3FFFF) * EMB + c0];
            cbA = *(const float4*)&combo[(size_t)(pkA >> 18) * EMB + c0];
        }
        for (int e = beg; e < end; ++e) {
            const float4 xvC = xvA, cbC = cbA;
            const float wC = wA;
            pkA = pkB; wA = wB;
            if (e + 1 < end) {
                xvA = *(const float4*)&XLin[(size_t)(pkA & 0x3FFFF) * EMB + c0];
                cbA = *(const float4*)&combo[(size_t)(pkA >> 18) * EMB + c0];
            }
            if (e + 2 < end) { pkB = epk[e + 2]; wB = enrm[e + 2]; }
            acc.x += fmaxf(xvC.x + cbC.x, 0.f) * wC;
            acc.y += fmaxf(xvC.y + cbC.y, 0.f) * wC;
            acc.z += fmaxf(xvC.z + cbC.z, 0.f) * wC;
            acc.w += fmaxf(xvC.w + cbC.w, 0.f) * wC;
        }
        // BN4 (no relu), accumulate per-graph partial in registers
        seg.x += fmaf(acc.x, s4.x, t4.x);
        seg.y += fmaf(acc.y, s4.y, t4.y);
        seg.z += fmaf(acc.z, s4.z, t4.z);
        seg.w += fmaf(acc.w, s4.w, t4.w);
    }
    *(float4*)&red[hw][c0] = seg;
    __syncthreads();

    const int t = threadIdx.x;
    if (t < EMB) {
        float v = 0.f;
#pragma unroll
        for (int r = 0; r < 16; ++r) v += red[r][t];
        hr[t] = v;
    }
    __syncthreads();
    if (t < EMB) {
        float o = hb[t];
#pragma unroll 8
        for (int k = 0; k < EMB; ++k) o = fmaf(hr[k], HW[(size_t)k * EMB + t], o);
        OUT[(size_t)gph * EMB + t] = o;
    }
}

extern "C" void kernel_launch(void* const* d_in, const int* in_sizes, int n_in,
                              void* d_out, int out_size, void* d_ws, size_t ws_size,
                              hipStream_t stream) {
    const int*   x     = (const int*)d_in[0];
    const int*   ei    = (const int*)d_in[1];    // [2, E]: src then dst
    const int*   ea    = (const int*)d_in[2];    // [E, 3]
    const int*   batch = (const int*)d_in[3];
    const float* aemb  = (const float*)d_in[4];
    const float* bemb  = (const float*)d_in[5];
    const float* W     = (const float*)d_in[6];
    const float* b     = (const float*)d_in[7];
    const float* root  = (const float*)d_in[8];
    const float* bnm   = (const float*)d_in[9];
    const float* bnv   = (const float*)d_in[10];
    const float* bng   = (const float*)d_in[11];
    const float* bnb   = (const float*)d_in[12];
    const float* hW    = (const float*)d_in[13];
    const float* hb    = (const float*)d_in[14];
    float* out = (float*)d_out;

    const size_t NF = (size_t)N_NODES * EMB;
    const size_t n_float = 2 * NF + (size_t)LAYERS * 512 * EMB
                         + 2 * LAYERS * EMB + N_EDGES
                         + 2 * ((size_t)LAYERS * 16384 / 2 + 64);
    const size_t n_int   = 3 * (size_t)N_NODES + (N_NODES + 4) + 128
                         + (N_GRAPHS + 4) + N_EDGES;
    const size_t need = (n_float + n_int) * sizeof(float);
    if (ws_size < need) return;  // defensive: fail cleanly, don't fault

    float* f     = (float*)d_ws;
    float* bufA  = f;                          f += NF;
    float* bufB  = f;                          f += NF;
    float* combo = f;                          f += (size_t)LAYERS * 512 * EMB;
    float* S     = f;                          f += LAYERS * EMB;
    float* T     = f;                          f += LAYERS * EMB;
    float* enrm  = f;                          f += N_EDGES;
    unsigned short* whi = (unsigned short*)f;  f += (size_t)LAYERS * 16384 / 2 + 64;
    unsigned short* wlo = (unsigned short*)f;  f += (size_t)LAYERS * 16384 / 2 + 64;
    int*   ip    = (int*)f;
    int*   dsrc    = ip;                       ip += N_NODES;
    int*   ddst    = ip;                       ip += N_NODES;
    int*   fill    = ip;                       ip += N_NODES;
    int*   rowptr  = ip;                       ip += N_NODES + 4;
    int*   partial = ip;                       ip += 128;
    int*   gptr    = ip;                       ip += N_GRAPHS + 4;
    int*   epk     = ip;                       ip += N_EDGES;

    hipMemsetAsync(dsrc, 0, 3 * (size_t)N_NODES * sizeof(int), stream);

    prep_all<<<PREP_BLOCKS, 256, 0, stream>>>(
        ei, ei + N_EDGES, dsrc, ddst, W, whi, wlo, bemb, combo,
        bnm, bnv, bng, bnb, S, T, batch, gptr);
    scan1<<<N_CHUNKS, 256, 0, stream>>>(ddst, partial);
    scan3<<<N_CHUNKS, 256, 0, stream>>>(ddst, partial, rowptr);
    scatter_k<<<(N_EDGES + 255) / 256, 256, 0, stream>>>(ei, ei + N_EDGES, ea, dsrc,
                                                         rowptr, fill, epk, enrm);

    // L0: encoder fused with GEMM-0 -> XL0 in bufA
    enc_gemm<<<N_NODES / 32, 1024, 0, stream>>>(x, aemb, whi, wlo, b, bufA);

    // L0..L3 gathers fused with next layer's GEMM; h stays on-chip.
    float* in    = bufA;
    float* other = bufB;
    for (int l = 0; l < 4; ++l) {
        gather_gemm<<<N_NODES / 32, 1024, 0, stream>>>(
            rowptr, epk, enrm, combo + (size_t)l * 512 * EMB, root + l * EMB, dsrc,
            S + l * EMB, T + l * EMB,
            whi + (size_t)(l + 1) * 16384, wlo + (size_t)(l + 1) * 16384,
            b + (l + 1) * EMB, /*XLin=*/in, /*XLout=*/other);
        float* t0 = in; in = other; other = t0;
    }

    // L4 gather fused with BN4 + pool + head, one block per graph, no atomics
    gather_pool_head<<<N_GRAPHS, 512, 0, stream>>>(
        rowptr, epk, enrm, combo + (size_t)4 * 512 * EMB, root + 4 * EMB, dsrc,
        S + 4 * EMB, T + 4 * EMB, gptr, /*XLin=*/in, hW, hb, out);
}

// Round 9
// 716.364 us; speedup vs baseline: 1.2018x; 1.2018x over previous
//
#include <hip/hip_runtime.h>
#include <hip/hip_bf16.h>

#define N_NODES 200000
#define N_EDGES 600000
#define N_GRAPHS 4000
#define EMB 128
#define LAYERS 5
#define BN_EPS 1e-5f

#define SCAN_CHUNK 2048                   // 256 threads x 8
#define N_CHUNKS ((N_NODES + SCAN_CHUNK - 1) / SCAN_CHUNK)   // 98

typedef __attribute__((ext_vector_type(8))) short short8;   // 8 bf16 (4 VGPRs)
typedef __attribute__((ext_vector_type(4))) float float4v;  // MFMA C/D

// split f32 -> bf16 hi (truncate) + bf16 lo (truncate of residual)
__device__ __forceinline__ void bf16split(float f, unsigned short& hi, unsigned short& lo) {
    unsigned u = __float_as_uint(f);
    hi = (unsigned short)(u >> 16);
    float hf = __uint_as_float((unsigned)hi << 16);
    lo = (unsigned short)(__float_as_uint(f - hf) >> 16);
}

// ---------------------------------------------------------------------------
// Fused prep kernel: 5 independent jobs partitioned by blockIdx.
// ---------------------------------------------------------------------------
#define CNT_BLOCKS 2344
#define WP_BASE   CNT_BLOCKS
#define WP_BLOCKS 320
#define CB_BASE   (WP_BASE + WP_BLOCKS)
#define CB_BLOCKS 1280
#define BN_BASE   (CB_BASE + CB_BLOCKS)
#define BN_BLOCKS 3
#define GB_BASE   (BN_BASE + BN_BLOCKS)
#define GB_BLOCKS 16
#define PREP_BLOCKS (GB_BASE + GB_BLOCKS)

__global__ __launch_bounds__(256) void prep_all(
    const int* __restrict__ ei_src, const int* __restrict__ ei_dst,
    int* __restrict__ dsrc, int* __restrict__ ddst,
    const float* __restrict__ W, unsigned short* __restrict__ whi,
    unsigned short* __restrict__ wlo,
    const float* __restrict__ bemb, float* __restrict__ combo,
    const float* __restrict__ mean, const float* __restrict__ var,
    const float* __restrict__ gamma, const float* __restrict__ beta,
    float* __restrict__ S, float* __restrict__ T,
    const int* __restrict__ batch, int* __restrict__ gptr) {
    const int b = blockIdx.x, tid = threadIdx.x;
    if (b < CNT_BLOCKS) {
        const int e = b * 256 + tid;
        if (e < N_EDGES) {
            atomicAdd(&dsrc[ei_src[e]], 1);
            atomicAdd(&ddst[ei_dst[e]], 1);
        }
    } else if (b < CB_BASE) {
        const int idx = (b - WP_BASE) * 256 + tid;      // < 81920, exact
        const int l = idx >> 14, rem = idx & 16383;
        const int k = rem >> 7, n = rem & 127;
        unsigned short hi, lo;
        bf16split(W[idx], hi, lo);
        const int off = (l << 14) + ((((k >> 5) * 8 + (n >> 4)) * 64
                        + ((k >> 3) & 3) * 16 + (n & 15)) << 3) + (k & 7);
        whi[off] = hi;
        wlo[off] = lo;
    } else if (b < BN_BASE) {
        const int idx = (b - CB_BASE) * 256 + tid;      // < 327680, exact
        const int l = idx >> 16;
        const int c = (idx >> 7) & 511;
        const int ch = idx & 127;
        const int a0 = c & 7, a1 = (c >> 3) & 7, a2 = c >> 6;
        combo[(size_t)(l * 512 + c) * EMB + ch] =
            bemb[(size_t)((l * 3 + 0) * 8 + a0) * EMB + ch] +
            bemb[(size_t)((l * 3 + 1) * 8 + a1) * EMB + ch] +
            bemb[(size_t)((l * 3 + 2) * 8 + a2) * EMB + ch];
    } else if (b < GB_BASE) {
        const int i = (b - BN_BASE) * 256 + tid;
        if (i < LAYERS * EMB) {
            float s = gamma[i] / sqrtf(var[i] + BN_EPS);
            S[i] = s;
            T[i] = beta[i] - mean[i] * s;
        }
    } else {
        const int g = (b - GB_BASE) * 256 + tid;
        if (g > N_GRAPHS) return;
        if (g == N_GRAPHS) { gptr[g] = N_NODES; return; }
        int lo = 0, hi = N_NODES;
        while (lo < hi) {
            int mid = (lo + hi) >> 1;
            if (batch[mid] < g) lo = mid + 1; else hi = mid;
        }
        gptr[g] = lo;
    }
}

// ---------------------------------------------------------------------------
// scan1: per-chunk sums of ddst
// ---------------------------------------------------------------------------
__global__ __launch_bounds__(256) void scan1(const int* __restrict__ deg, int* __restrict__ partial) {
    __shared__ int sd[256];
    const int base = blockIdx.x * SCAN_CHUNK + threadIdx.x * 8;
    int s = 0;
#pragma unroll
    for (int i = 0; i < 8; ++i) { int idx = base + i; s += (idx < N_NODES) ? deg[idx] : 0; }
    sd[threadIdx.x] = s; __syncthreads();
    for (int off = 128; off > 0; off >>= 1) {
        if (threadIdx.x < off) sd[threadIdx.x] += sd[threadIdx.x + off];
        __syncthreads();
    }
    if (threadIdx.x == 0) partial[blockIdx.x] = sd[0];
}

// ---------------------------------------------------------------------------
// scan3: block computes its own offset from partials, then scans its chunk.
// ---------------------------------------------------------------------------
__global__ __launch_bounds__(256) void scan3(const int* __restrict__ deg,
                                             const int* __restrict__ partial,
                                             int* __restrict__ rowptr) {
    __shared__ int sd[256];
    __shared__ int base_off;
    const int tid = threadIdx.x;
    if (tid == 0) {
        int acc = 0;
        for (int i = 0; i < (int)blockIdx.x; ++i) acc += partial[i];
        base_off = acc;
    }
    const int base = blockIdx.x * SCAN_CHUNK + tid * 8;
    int loc[8]; int s = 0;
#pragma unroll
    for (int i = 0; i < 8; ++i) { int idx = base + i; loc[i] = (idx < N_NODES) ? deg[idx] : 0; s += loc[i]; }
    sd[tid] = s; __syncthreads();
    for (int off = 1; off < 256; off <<= 1) {
        int v = (tid >= off) ? sd[tid - off] : 0;
        __syncthreads();
        sd[tid] += v;
        __syncthreads();
    }
    int excl = base_off + sd[tid] - s;
#pragma unroll
    for (int i = 0; i < 8; ++i) {
        int idx = base + i;
        if (idx < N_NODES) { rowptr[idx] = excl; excl += loc[i]; }
    }
    if (blockIdx.x == 0 && tid == 0) rowptr[N_NODES] = N_EDGES;
}

// ---------------------------------------------------------------------------
// Scatter edges into dst-CSR. Record: epk = src | combo<<18 ; enrm = norm.
// ---------------------------------------------------------------------------
__global__ void scatter_k(const int* __restrict__ srcs, const int* __restrict__ dsts,
                          const int* __restrict__ eattr, const int* __restrict__ dsrc,
                          const int* __restrict__ rowptr, int* __restrict__ fill,
                          int* __restrict__ epk, float* __restrict__ enrm) {
    int e = blockIdx.x * blockDim.x + threadIdx.x;
    if (e >= N_EDGES) return;
    const int s = srcs[e];
    const int d = dsts[e];
    const int pos = rowptr[d] + atomicAdd(&fill[d], 1);
    const int c = eattr[e * 3] | (eattr[e * 3 + 1] << 3) | (eattr[e * 3 + 2] << 6);
    epk[pos] = s | (c << 18);
    enrm[pos] = rsqrtf((float)(dsrc[s] + 1) * (float)(dsrc[d] + 1));
}

// ---------------------------------------------------------------------------
// MFMA phase for 1024-thread blocks: 32 rows x 128 cols, 16 waves, one 16x16
// C-tile each over K=128 (4 ksteps x 3 split-terms). C is staged through LDS
// (reusing the A tiles, stride 132 -> 2-way-only bank aliasing) so the global
// store is one contiguous float4 per thread = full 128B lines per wave
// (avoids the 64B partial-line write-allocate refetch seen in r7: FETCH
// tracked WRITE ~1:1 at 200MB).
// ---------------------------------------------------------------------------
__device__ __forceinline__ void mfma_tile32(
    unsigned short (*AhAl)[32][136],
    const short8* __restrict__ Bh, const short8* __restrict__ Bl,
    const float* __restrict__ bias, float* __restrict__ XLout,
    size_t rows, int tid) {
    const int wave = tid >> 6;          // 0..15
    const int lane = tid & 63;
    const int quad = lane >> 4;
    const int n15  = lane & 15;
    const int rt   = wave & 1;          // row-tile
    const int ct   = wave >> 1;         // col-tile 0..7
    const int arow = rt * 16 + n15;

    float4v acc = (float4v)(0.f);
#pragma unroll
    for (int ks = 0; ks < 4; ++ks) {
        const int k0 = ks * 32 + quad * 8;
        const short8 ah = *(const short8*)&AhAl[0][arow][k0];
        const short8 al = *(const short8*)&AhAl[1][arow][k0];
        const short8 bh = Bh[(ks * 8 + ct) * 64 + lane];
        const short8 bl = Bl[(ks * 8 + ct) * 64 + lane];
        acc = __builtin_amdgcn_mfma_f32_16x16x32_bf16(ah, bh, acc, 0, 0, 0);
        acc = __builtin_amdgcn_mfma_f32_16x16x32_bf16(ah, bl, acc, 0, 0, 0);
        acc = __builtin_amdgcn_mfma_f32_16x16x32_bf16(al, bh, acc, 0, 0, 0);
    }

    __syncthreads();                    // done reading A tiles; reuse as C
    float* Cf = (float*)AhAl;           // 32 x 132 floats = 16896 B (fits 17408)
    const int crow = rt * 16 + quad * 4;
    const int col  = ct * 16 + n15;
    const float bc = bias[col];
#pragma unroll
    for (int r = 0; r < 4; ++r)
        Cf[(crow + r) * 132 + col] = acc[r] + bc;
    __syncthreads();

    const int orow = tid >> 5;
    const int c4   = (tid & 31) * 4;
    const float4 v = *(const float4*)&Cf[orow * 132 + c4];
    *(float4*)&XLout[(rows + orow) * EMB + c4] = v;
}

// ---------------------------------------------------------------------------
// Fused atom-encoder + GEMM layer 0 (1024 threads): 32 half-waves x 1 row.
// ---------------------------------------------------------------------------
__global__ __launch_bounds__(1024, 8) void enc_gemm(
    const int* __restrict__ x, const float* __restrict__ aemb,
    const unsigned short* __restrict__ whi, const unsigned short* __restrict__ wlo,
    const float* __restrict__ bias, float* __restrict__ XL) {
    __shared__ unsigned short AhAl[2][32][136];
    const int tid = threadIdx.x;
    const int g = tid & 31, hw = tid >> 5;     // 32 half-waves
    const int c0 = g * 4;
    const size_t rows = (size_t)blockIdx.x * 32;

    {
        const size_t n = rows + hw;
        float4 acc = make_float4(0.f, 0.f, 0.f, 0.f);
#pragma unroll
        for (int ff = 0; ff < 9; ++ff) {
            const int v = x[n * 9 + ff];
            const float4 e = *(const float4*)&aemb[(size_t)(ff * 64 + v) * EMB + c0];
            acc.x += e.x; acc.y += e.y; acc.z += e.z; acc.w += e.w;
        }
        ushort4 hi, lo;
        bf16split(acc.x, hi.x, lo.x);
        bf16split(acc.y, hi.y, lo.y);
        bf16split(acc.z, hi.z, lo.z);
        bf16split(acc.w, hi.w, lo.w);
        *(ushort4*)&AhAl[0][hw][c0] = hi;
        *(ushort4*)&AhAl[1][hw][c0] = lo;
    }
    __syncthreads();
    mfma_tile32(AhAl, (const short8*)whi, (const short8*)wlo, bias, XL, rows, tid);
}

// ---------------------------------------------------------------------------
// Fused gather(layer l) + BN_l + ReLU + GEMM(layer l+1) (1024 threads):
// 32 half-waves x 1 node gather (simple depth-1 edge-record prefetch, the
// r6 structure that measured 105.7us) -> LDS bf16 split -> 16-wave MFMA.
// ---------------------------------------------------------------------------
__global__ __launch_bounds__(1024, 8) void gather_gemm(
    const int* __restrict__ rowptr, const int* __restrict__ epk,
    const float* __restrict__ enrm, const float* __restrict__ combo,
    const float* __restrict__ root, const int* __restrict__ dsrc,
    const float* __restrict__ bnS, const float* __restrict__ bnT,
    const unsigned short* __restrict__ whi, const unsigned short* __restrict__ wlo,
    const float* __restrict__ bias,
    const float* __restrict__ XLin, float* __restrict__ XLout) {
    __shared__ unsigned short AhAl[2][32][136];
    const int tid = threadIdx.x;
    const int g = tid & 31, hw = tid >> 5;
    const int c0 = g * 4;
    const size_t rows = (size_t)blockIdx.x * 32;

    {
        const size_t n = rows + hw;
        const float4 r4 = *(const float4*)&root[c0];
        const float4 s4 = *(const float4*)&bnS[c0];
        const float4 t4 = *(const float4*)&bnT[c0];
        const float dinv = 1.0f / (float)(dsrc[n] + 1);
        const float4 xn = *(const float4*)&XLin[n * EMB + c0];
        float4 acc;
        acc.x = fmaxf(xn.x + r4.x, 0.f) * dinv;
        acc.y = fmaxf(xn.y + r4.y, 0.f) * dinv;
        acc.z = fmaxf(xn.z + r4.z, 0.f) * dinv;
        acc.w = fmaxf(xn.w + r4.w, 0.f) * dinv;
        const int beg = rowptr[n], end = rowptr[n + 1];
        int pk = 0; float wgt = 0.f;
        if (beg < end) { pk = epk[beg]; wgt = enrm[beg]; }
        for (int e = beg; e < end; ++e) {
            const int pk_c = pk; const float w_c = wgt;
            if (e + 1 < end) { pk = epk[e + 1]; wgt = enrm[e + 1]; }   // prefetch
            const int s = pk_c & 0x3FFFF;
            const int c = pk_c >> 18;
            const float4 xv = *(const float4*)&XLin[(size_t)s * EMB + c0];
            const float4 cb = *(const float4*)&combo[(size_t)c * EMB + c0];
            acc.x += fmaxf(xv.x + cb.x, 0.f) * w_c;
            acc.y += fmaxf(xv.y + cb.y, 0.f) * w_c;
            acc.z += fmaxf(xv.z + cb.z, 0.f) * w_c;
            acc.w += fmaxf(xv.w + cb.w, 0.f) * w_c;
        }
        float4 h;
        h.x = fmaxf(fmaf(acc.x, s4.x, t4.x), 0.f);
        h.y = fmaxf(fmaf(acc.y, s4.y, t4.y), 0.f);
        h.z = fmaxf(fmaf(acc.z, s4.z, t4.z), 0.f);
        h.w = fmaxf(fmaf(acc.w, s4.w, t4.w), 0.f);
        ushort4 hi, lo;
        bf16split(h.x, hi.x, lo.x);
        bf16split(h.y, hi.y, lo.y);
        bf16split(h.z, hi.z, lo.z);
        bf16split(h.w, hi.w, lo.w);
        *(ushort4*)&AhAl[0][hw][c0] = hi;
        *(ushort4*)&AhAl[1][hw][c0] = lo;
    }
    __syncthreads();
    mfma_tile32(AhAl, (const short8*)whi, (const short8*)wlo, bias, XLout, rows, tid);
}

// ---------------------------------------------------------------------------
// Fused final gather(layer 4) + BN4 + pool + head. One 512-thread block per
// graph: 16 half-waves stride the graph's nodes with register partials;
// LDS reduce; in-block head matvec. No global atomics.
// ---------------------------------------------------------------------------
__global__ __launch_bounds__(512) void gather_pool_head(
    const int* __restrict__ rowptr, const int* __restrict__ epk,
    const float* __restrict__ enrm, const float* __restrict__ combo,
    const float* __restrict__ root, const int* __restrict__ dsrc,
    const float* __restrict__ S4, const float* __restrict__ T4,
    const int* __restrict__ gptr, const float* __restrict__ XLin,
    const float* __restrict__ HW, const float* __restrict__ hb,
    float* __restrict__ OUT) {
    __shared__ float red[16][EMB];
    __shared__ float hr[EMB];
    const int gph = blockIdx.x;
    const int g = threadIdx.x & 31, hw = threadIdx.x >> 5;   // 16 half-waves
    const int c0 = g * 4;
    const int nbeg = gptr[gph], nend = gptr[gph + 1];

    const float4 r4 = *(const float4*)&root[c0];
    const float4 s4 = *(const float4*)&S4[c0];
    const float4 t4 = *(const float4*)&T4[c0];

    float4 seg = make_float4(0.f, 0.f, 0.f, 0.f);
    for (int n = nbeg + hw; n < nend; n += 16) {
        const float dinv = 1.0f / (float)(dsrc[n] + 1);
        const float4 xn = *(const float4*)&XLin[(size_t)n * EMB + c0];
        float4 acc;
        acc.x = fmaxf(xn.x + r4.x, 0.f) * dinv;
        acc.y = fmaxf(xn.y + r4.y, 0.f) * dinv;
        acc.z = fmaxf(xn.z + r4.z, 0.f) * dinv;
        acc.w = fmaxf(xn.w + r4.w, 0.f) * dinv;
        const int beg = rowptr[n], end = rowptr[n + 1];
        int pk = 0; float wgt = 0.f;
        if (beg < end) { pk = epk[beg]; wgt = enrm[beg]; }
        for (int e = beg; e < end; ++e) {
            const int pk_c = pk; const float w_c = wgt;
            if (e + 1 < end) { pk = epk[e + 1]; wgt = enrm[e + 1]; }
            const int s = pk_c & 0x3FFFF;
            const int c = pk_c >> 18;
            const float4 xv = *(const float4*)&XLin[(size_t)s * EMB + c0];
            const float4 cb = *(const float4*)&combo[(size_t)c * EMB + c0];
            acc.x += fmaxf(xv.x + cb.x, 0.f) * w_c;
            acc.y += fmaxf(xv.y + cb.y, 0.f) * w_c;
            acc.z += fmaxf(xv.z + cb.z, 0.f) * w_c;
            acc.w += fmaxf(xv.w + cb.w, 0.f) * w_c;
        }
        seg.x += fmaf(acc.x, s4.x, t4.x);
        seg.y += fmaf(acc.y, s4.y, t4.y);
        seg.z += fmaf(acc.z, s4.z, t4.z);
        seg.w += fmaf(acc.w, s4.w, t4.w);
    }
    *(float4*)&red[hw][c0] = seg;
    __syncthreads();

    const int t = threadIdx.x;
    if (t < EMB) {
        float v = 0.f;
#pragma unroll
        for (int r = 0; r < 16; ++r) v += red[r][t];
        hr[t] = v;
    }
    __syncthreads();
    if (t < EMB) {
        float o = hb[t];
#pragma unroll 8
        for (int k = 0; k < EMB; ++k) o = fmaf(hr[k], HW[(size_t)k * EMB + t], o);
        OUT[(size_t)gph * EMB + t] = o;
    }
}

extern "C" void kernel_launch(void* const* d_in, const int* in_sizes, int n_in,
                              void* d_out, int out_size, void* d_ws, size_t ws_size,
                              hipStream_t stream) {
    const int*   x     = (const int*)d_in[0];
    const int*   ei    = (const int*)d_in[1];    // [2, E]: src then dst
    const int*   ea    = (const int*)d_in[2];    // [E, 3]
    const int*   batch = (const int*)d_in[3];
    const float* aemb  = (const float*)d_in[4];
    const float* bemb  = (const float*)d_in[5];
    const float* W     = (const float*)d_in[6];
    const float* b     = (const float*)d_in[7];
    const float* root  = (const float*)d_in[8];
    const float* bnm   = (const float*)d_in[9];
    const float* bnv   = (const float*)d_in[10];
    const float* bng   = (const float*)d_in[11];
    const float* bnb   = (const float*)d_in[12];
    const float* hW    = (const float*)d_in[13];
    const float* hb    = (const float*)d_in[14];
    float* out = (float*)d_out;

    const size_t NF = (size_t)N_NODES * EMB;
    const size_t n_float = 2 * NF + (size_t)LAYERS * 512 * EMB
                         + 2 * LAYERS * EMB + N_EDGES
                         + 2 * ((size_t)LAYERS * 16384 / 2 + 64);
    const size_t n_int   = 3 * (size_t)N_NODES + (N_NODES + 4) + 128
                         + (N_GRAPHS + 4) + N_EDGES;
    const size_t need = (n_float + n_int) * sizeof(float);
    if (ws_size < need) return;  // defensive: fail cleanly, don't fault

    float* f     = (float*)d_ws;
    float* bufA  = f;                          f += NF;
    float* bufB  = f;                          f += NF;
    float* combo = f;                          f += (size_t)LAYERS * 512 * EMB;
    float* S     = f;                          f += LAYERS * EMB;
    float* T     = f;                          f += LAYERS * EMB;
    float* enrm  = f;                          f += N_EDGES;
    unsigned short* whi = (unsigned short*)f;  f += (size_t)LAYERS * 16384 / 2 + 64;
    unsigned short* wlo = (unsigned short*)f;  f += (size_t)LAYERS * 16384 / 2 + 64;
    int*   ip    = (int*)f;
    int*   dsrc    = ip;                       ip += N_NODES;
    int*   ddst    = ip;                       ip += N_NODES;
    int*   fill    = ip;                       ip += N_NODES;
    int*   rowptr  = ip;                       ip += N_NODES + 4;
    int*   partial = ip;                       ip += 128;
    int*   gptr    = ip;                       ip += N_GRAPHS + 4;
    int*   epk     = ip;                       ip += N_EDGES;

    hipMemsetAsync(dsrc, 0, 3 * (size_t)N_NODES * sizeof(int), stream);

    prep_all<<<PREP_BLOCKS, 256, 0, stream>>>(
        ei, ei + N_EDGES, dsrc, ddst, W, whi, wlo, bemb, combo,
        bnm, bnv, bng, bnb, S, T, batch, gptr);
    scan1<<<N_CHUNKS, 256, 0, stream>>>(ddst, partial);
    scan3<<<N_CHUNKS, 256, 0, stream>>>(ddst, partial, rowptr);
    scatter_k<<<(N_EDGES + 255) / 256, 256, 0, stream>>>(ei, ei + N_EDGES, ea, dsrc,
                                                         rowptr, fill, epk, enrm);

    // L0: encoder fused with GEMM-0 -> XL0 in bufA
    enc_gemm<<<N_NODES / 32, 1024, 0, stream>>>(x, aemb, whi, wlo, b, bufA);

    // L0..L3 gathers fused with next layer's GEMM; h stays on-chip.
    float* in    = bufA;
    float* other = bufB;
    for (int l = 0; l < 4; ++l) {
        gather_gemm<<<N_NODES / 32, 1024, 0, stream>>>(
            rowptr, epk, enrm, combo + (size_t)l * 512 * EMB, root + l * EMB, dsrc,
            S + l * EMB, T + l * EMB,
            whi + (size_t)(l + 1) * 16384, wlo + (size_t)(l + 1) * 16384,
            b + (l + 1) * EMB, /*XLin=*/in, /*XLout=*/other);
        float* t0 = in; in = other; other = t0;
    }

    // L4 gather fused with BN4 + pool + head, one block per graph, no atomics
    gather_pool_head<<<N_GRAPHS, 512, 0, stream>>>(
        rowptr, epk, enrm, combo + (size_t)4 * 512 * EMB, root + 4 * EMB, dsrc,
        S + 4 * EMB, T + 4 * EMB, gptr, /*XLin=*/in, hW, hb, out);
}